// Round 22
// baseline (533.009 us; speedup 1.0000x reference)
//
#include <hip/hip_runtime.h>
#include <stdint.h>

typedef _Float16 f16;
typedef unsigned short u16;
typedef __attribute__((ext_vector_type(8))) _Float16 h16x8;
typedef __attribute__((ext_vector_type(8))) unsigned short u16x8;
typedef __attribute__((ext_vector_type(4))) float f32x4;

#define NDIM  4096
#define KDIM  4096
#define LRDIM 64
#define NTK   128        // KDIM / 32

#define MFMA16(a, b, c) __builtin_amdgcn_mfma_f32_16x16x32_f16((a), (b), (c), 0, 0, 0)

__device__ __forceinline__ float bf2f(u16 b) {
  union { unsigned u; float f; } c; c.u = ((unsigned)b) << 16; return c.f;
}
__device__ __forceinline__ float h2f(u16 b) {
  union { u16 u; f16 h; } c; c.u = b; return (float)c.h;
}
__device__ __forceinline__ h16x8 pack8(float4 a, float4 b) {
  h16x8 w = { (f16)a.x, (f16)a.y, (f16)a.z, (f16)a.w,
              (f16)b.x, (f16)b.y, (f16)b.z, (f16)b.w };
  return w;
}

// async global->LDS, 16B/lane; true addrspacecast (proven green r10-r21).
__device__ __forceinline__ void gll16(const void* g, void* l) {
  __builtin_amdgcn_global_load_lds(
      (const __attribute__((address_space(1))) void*)g,
      (__attribute__((address_space(3))) void*)l,
      16, 0, 0);
}

// ---------------------------------------------------------------------------
// frozen encoding classifier (proven): 0=f16, 1=bf16, 2=f32 halfword layout.
// ---------------------------------------------------------------------------
__device__ int frozen_mode(const void* frozen, int t) {
  const u16* fr = (const u16*)frozen;
  __shared__ int sE[256], sO[256];
  int ce = 0, co = 0;
  for (int j = 0; j < 8; ++j) {
    float ve = fabsf(bf2f(fr[t * 16 + 2 * j]));
    float vo = fabsf(bf2f(fr[t * 16 + 2 * j + 1]));
    if (ve >= 0.05f && ve <= 10.0f) ++ce;
    if (vo >= 0.05f && vo <= 10.0f) ++co;
  }
  sE[t] = ce; sO[t] = co;
  __syncthreads();
  for (int s = 128; s > 0; s >>= 1) {
    if (t < s) { sE[t] += sE[t + s]; sO[t] += sO[t + s]; }
    __syncthreads();
  }
  int te = sE[0], to = sO[0];
  __syncthreads();
  if (to > 1024) return (te > 1024) ? 1 : 2;
  return 0;
}

__device__ __forceinline__ h16x8 build_m8(
    const void* __restrict__ frozen, const float* __restrict__ gs,
    const float* __restrict__ gb, const float* __restrict__ sa,
    int o, int i0, int mode)
{
  size_t fo = (size_t)o * KDIM + i0;
  int gidx = (o >> 3) * 512 + (i0 >> 3);
  float gsf = gs[gidx], gbf = gb[gidx];
  float4 s0 = ((const float4*)(sa + fo))[0];
  float4 s1 = ((const float4*)(sa + fo))[1];
  float sv[8] = { s0.x, s0.y, s0.z, s0.w, s1.x, s1.y, s1.z, s1.w };
  float fv[8];
  if (mode == 2) {
    float4 q0 = ((const float4*)((const float*)frozen + fo))[0];
    float4 q1 = ((const float4*)((const float*)frozen + fo))[1];
    fv[0]=q0.x; fv[1]=q0.y; fv[2]=q0.z; fv[3]=q0.w;
    fv[4]=q1.x; fv[5]=q1.y; fv[6]=q1.z; fv[7]=q1.w;
  } else {
    u16x8 fb = *(const u16x8*)((const u16*)frozen + fo);
#pragma unroll
    for (int j = 0; j < 8; ++j) fv[j] = (mode == 1) ? bf2f(fb[j]) : h2f(fb[j]);
  }
  h16x8 w;
#pragma unroll
  for (int j = 0; j < 8; ++j) w[j] = (f16)(gbf + fv[j] * gsf + sv[j]);
  return w;
}

// ---------------------------------------------------------------------------
// k_prep2: one launch for ALL prep.
//   blocks 0..16383     : cast x -> xh (f16)
//   blocks 16384..24575 : build mW (f16)
//   blocks 24576..24639 : hid = f16(x) @ L1^T  (r9-proven k9_hid body,
//                         reads f32 x directly -> no xh dependency)
// ---------------------------------------------------------------------------
__global__ __launch_bounds__(256) void k_prep2(
    const float* __restrict__ x, const void* __restrict__ frozen,
    const float* __restrict__ gs, const float* __restrict__ gb,
    const float* __restrict__ sa, const float* __restrict__ L1,
    f16* __restrict__ xh, f16* __restrict__ mW, f16* __restrict__ hid)
{
  __shared__ f16 sA[2][128 * 32];
  __shared__ f16 sB[2][64 * 32];
  int b = blockIdx.x;
  int t = threadIdx.x;

  if (b < 16384) {
    size_t idx = (size_t)b * 256 + t;
    const float4* xp = (const float4*)x + idx * 2;
    *(h16x8*)(xh + idx * 8) = pack8(xp[0], xp[1]);
    return;
  }
  if (b < 24576) {
    int mode = frozen_mode(frozen, t);
    int idx = (b - 16384) * 256 + t;
    int o  = idx >> 9;
    int ig = idx & 511;
    h16x8 w = build_m8(frozen, gs, gb, sa, o, ig * 8, mode);
    *(h16x8*)(mW + (size_t)o * KDIM + ig * 8) = w;
    return;
  }

  // ---- hid branch (r9-proven k9_hid, verbatim) ----
  int l = t & 63, wid = t >> 6;
  int wr = wid >> 1, wc = wid & 1;
  int brow = (b - 24576) * 128;
  int arow = t >> 1, acol = (t & 1) * 16;
  int brw = t >> 2, bc8 = (t & 3) * 8;

  f32x4 acc[4][2] = {};

  {
    const float* ap = x + (size_t)(brow + arow) * KDIM + acol;
    float4 v0 = ((const float4*)ap)[0], v1 = ((const float4*)ap)[1];
    float4 v2 = ((const float4*)ap)[2], v3 = ((const float4*)ap)[3];
    *(h16x8*)&sA[0][arow * 32 + acol]     = pack8(v0, v1);
    *(h16x8*)&sA[0][arow * 32 + acol + 8] = pack8(v2, v3);
    const float* lp = L1 + (size_t)brw * KDIM + bc8;
    *(h16x8*)&sB[0][brw * 32 + bc8] = pack8(((const float4*)lp)[0], ((const float4*)lp)[1]);
  }

  int cur = 0;
  for (int kt = 0; kt < NTK; ++kt) {
    __syncthreads();
    bool pf = (kt + 1 < NTK);
    h16x8 wa0, wa1, wb;
    if (pf) {
      int k0 = (kt + 1) * 32;
      const float* ap = x + (size_t)(brow + arow) * KDIM + k0 + acol;
      float4 v0 = ((const float4*)ap)[0], v1 = ((const float4*)ap)[1];
      float4 v2 = ((const float4*)ap)[2], v3 = ((const float4*)ap)[3];
      wa0 = pack8(v0, v1); wa1 = pack8(v2, v3);
      const float* lp = L1 + (size_t)brw * KDIM + k0 + bc8;
      wb = pack8(((const float4*)lp)[0], ((const float4*)lp)[1]);
    }
    h16x8 aF[4], bF[2];
#pragma unroll
    for (int m = 0; m < 4; ++m)
      aF[m] = *(const h16x8*)&sA[cur][(wr * 64 + m * 16 + (l & 15)) * 32 + (l >> 4) * 8];
#pragma unroll
    for (int n = 0; n < 2; ++n)
      bF[n] = *(const h16x8*)&sB[cur][(wc * 32 + n * 16 + (l & 15)) * 32 + (l >> 4) * 8];
#pragma unroll
    for (int m = 0; m < 4; ++m)
#pragma unroll
      for (int n = 0; n < 2; ++n)
        acc[m][n] = MFMA16(aF[m], bF[n], acc[m][n]);
    if (pf) {
      *(h16x8*)&sA[cur ^ 1][arow * 32 + acol]     = wa0;
      *(h16x8*)&sA[cur ^ 1][arow * 32 + acol + 8] = wa1;
      *(h16x8*)&sB[cur ^ 1][brw * 32 + bc8]       = wb;
    }
    cur ^= 1;
  }

#pragma unroll
  for (int m = 0; m < 4; ++m)
#pragma unroll
    for (int n = 0; n < 2; ++n)
#pragma unroll
      for (int j = 0; j < 4; ++j) {
        int r = wr * 64 + m * 16 + ((l >> 4) << 2) + j;
        int c = wc * 32 + n * 16 + (l & 15);
        hid[(size_t)(brow + r) * LRDIM + c] = (f16)acc[m][n][j];
      }
}

// ---------------------------------------------------------------------------
// k20_main: r21's proven 256x128 kernel with 64x64 wave tiles (4M x 2N):
// per-wave LDS reads drop 10 -> 8 b128 for the same 16 MFMAs (the LDS read
// pipe was the binding resource: 1920 vs MFMA 1229 cyc/CU/tile -> 1536).
// Schedule, swizzle, vmcnt (6/3/0), prologue: byte-identical to r21.
// ---------------------------------------------------------------------------
__global__ __launch_bounds__(512) void k20_main(
    const f16* __restrict__ xh, const f16* __restrict__ mW,
    const f16* __restrict__ hid, const float* __restrict__ L2,
    const float* __restrict__ scale, const float* __restrict__ bias,
    float* __restrict__ out)
{
  __shared__ f16 lds[3 * 12288];    // 3 x (A[256][32] + B[128][32]) = 73,728 B

  int t = threadIdx.x;              // 0..511
  int l = t & 63, wid = t >> 6;     // 8 waves
  int wm = wid >> 1, wn = wid & 1;  // wave tile: rows wm*64..+64, cols wn*64..+64

  // XCD 2-D chunked mapping: 1024 blocks = 8 XCDs x 128 (proven)
  int wg = blockIdx.x;
  int xcd = wg & 7, w = wg >> 3;
  int bm = xcd * 4 + (w & 3);       // 0..31
  int bn = w >> 2;                  // 0..31
  int brow = bm * 256, bcol = bn * 128;

  // stage one K-tile third (source-side swizzle: s_g = s_lds ^ ((r>>1)&3))
  auto stage = [&](int q, int kt2, int buf) {
    int u = q * 512 + t;            // 0..1535
    if (u < 1024) {
      int sg = (u & 3) ^ ((u >> 3) & 3);
      gll16(xh + (size_t)(brow + (u >> 2)) * KDIM + kt2 * 32 + sg * 8,
            &lds[buf * 12288 + u * 8]);
    } else {
      int v = u - 1024;
      int sg = (v & 3) ^ ((v >> 3) & 3);
      gll16(mW + (size_t)(bcol + (v >> 2)) * KDIM + kt2 * 32 + sg * 8,
            &lds[buf * 12288 + 8192 + v * 8]);
    }
  };

  // ---- prologue: stage K-tiles 0 (buf0) and 1 (buf1) ----
#pragma unroll
  for (int q = 0; q < 3; ++q) stage(q, 0, 0);
#pragma unroll
  for (int q = 0; q < 3; ++q) stage(q, 1, 1);

  f32x4 acc[4][4] = {};

  // read-side swizzle (lane-constant)
  int X = ((l >> 4) ^ ((l >> 1) & 3)) * 8;

  for (int kt = 0; kt < NTK; ++kt) {
    const f16* A = &lds[(kt % 3) * 12288];
    const f16* B = &lds[(kt % 3) * 12288 + 8192];
    int sb = (kt + 2) % 3;

    if (kt + 2 < NTK) {
#pragma unroll
      for (int q = 0; q < 3; ++q) stage(q, kt + 2, sb);
    }

    // residency gate for tile kt (3 loads/thread/tile)
    if (kt < NTK - 2) {
      asm volatile("s_waitcnt vmcnt(6)" ::: "memory");
    } else if (kt == NTK - 2) {
      asm volatile("s_waitcnt vmcnt(3)" ::: "memory");
    } else {
      asm volatile("s_waitcnt vmcnt(0)" ::: "memory");
    }
    __builtin_amdgcn_sched_barrier(0);
    __builtin_amdgcn_s_barrier();   // G: tile kt resident for all waves

    int ar0 = (wm * 64 + (l & 15)) * 32 + X;
    int br0 = (wn * 64 + (l & 15)) * 32 + X;

    h16x8 aF[4], bF[4];
#pragma unroll
    for (int f = 0; f < 4; ++f) aF[f] = *(const h16x8*)&A[ar0 + f * 512];
#pragma unroll
    for (int n = 0; n < 4; ++n) bF[n] = *(const h16x8*)&B[br0 + n * 512];

    __builtin_amdgcn_s_setprio(1);
#pragma unroll
    for (int f = 0; f < 4; ++f)
#pragma unroll
      for (int n = 0; n < 4; ++n)
        acc[f][n] = MFMA16(aF[f], bF[n], acc[f][n]);
    __builtin_amdgcn_s_setprio(0);

    __builtin_amdgcn_s_barrier();   // E: all reads of buf[kt%3] done
  }

  // ---- fused epilogue (r21-proven staging, 64x64-wave fragment indices) ----
  f16* sH  = &lds[0];               // [256][64] hid tile
  f16* sLm = &lds[16384];           // [128][64]
  f16* sLa = &lds[24576];           // [128][64]

#pragma unroll
  for (int q = 0; q < 4; ++q) {     // sH: 2048 16B-units
    int u = q * 512 + t;
    gll16(hid + (size_t)(brow + (u >> 3)) * LRDIM + (u & 7) * 8, &sH[u * 8]);
  }
#pragma unroll
  for (int q = 0; q < 2; ++q) {     // sLm: 1024 units
    int u = q * 512 + t;
    const float* lp = L2 + (size_t)(bcol + (u >> 3)) * LRDIM + (u & 7) * 8;
    *(h16x8*)&sLm[u * 8] = pack8(((const float4*)lp)[0], ((const float4*)lp)[1]);
  }
#pragma unroll
  for (int q = 0; q < 2; ++q) {     // sLa: 1024 units
    int u = q * 512 + t;
    const float* lq = L2 + (size_t)(NDIM + bcol + (u >> 3)) * LRDIM + (u & 7) * 8;
    *(h16x8*)&sLa[u * 8] = pack8(((const float4*)lq)[0], ((const float4*)lq)[1]);
  }
  __syncthreads();                  // full drain before reads

  float sc[4], bi[4];
#pragma unroll
  for (int n = 0; n < 4; ++n) {
    int o = bcol + wn * 64 + n * 16 + (l & 15);
    sc[n] = scale[o];
    bi[n] = bias[o];
  }

  // pass 1: mul = hid @ L2[0:4096]^T + scale ; acc <- mul * acc
  {
    h16x8 lB[4][2];
#pragma unroll
    for (int n = 0; n < 4; ++n)
#pragma unroll
      for (int kk = 0; kk < 2; ++kk)
        lB[n][kk] = *(const h16x8*)&sLm[(wn * 64 + n * 16 + (l & 15)) * 64 + kk * 32 + (l >> 4) * 8];
#pragma unroll
    for (int f = 0; f < 4; ++f) {
      h16x8 h0 = *(const h16x8*)&sH[(wm * 64 + f * 16 + (l & 15)) * 64 + (l >> 4) * 8];
      h16x8 h1 = *(const h16x8*)&sH[(wm * 64 + f * 16 + (l & 15)) * 64 + 32 + (l >> 4) * 8];
      f32x4 mm[4];
#pragma unroll
      for (int n = 0; n < 4; ++n) {
        f32x4 mi = { sc[n], sc[n], sc[n], sc[n] };
        mm[n] = mi;
      }
#pragma unroll
      for (int n = 0; n < 4; ++n) {
        mm[n] = MFMA16(h0, lB[n][0], mm[n]);
        mm[n] = MFMA16(h1, lB[n][1], mm[n]);
      }
#pragma unroll
      for (int n = 0; n < 4; ++n)
        acc[f][n] *= mm[n];
    }
  }

  // pass 2: add = hid @ L2[4096:8192]^T + bias ; out = add + acc
  {
    h16x8 lB[4][2];
#pragma unroll
    for (int n = 0; n < 4; ++n)
#pragma unroll
      for (int kk = 0; kk < 2; ++kk)
        lB[n][kk] = *(const h16x8*)&sLa[(wn * 64 + n * 16 + (l & 15)) * 64 + kk * 32 + (l >> 4) * 8];
#pragma unroll
    for (int f = 0; f < 4; ++f) {
      h16x8 h0 = *(const h16x8*)&sH[(wm * 64 + f * 16 + (l & 15)) * 64 + (l >> 4) * 8];
      h16x8 h1 = *(const h16x8*)&sH[(wm * 64 + f * 16 + (l & 15)) * 64 + 32 + (l >> 4) * 8];
      f32x4 aa[4];
#pragma unroll
      for (int n = 0; n < 4; ++n) {
        f32x4 mi = { bi[n], bi[n], bi[n], bi[n] };
        aa[n] = mi;
      }
#pragma unroll
      for (int n = 0; n < 4; ++n) {
        aa[n] = MFMA16(h0, lB[n][0], aa[n]);
        aa[n] = MFMA16(h1, lB[n][1], aa[n]);
      }
      int rbase = brow + wm * 64 + f * 16 + ((l >> 4) << 2);
#pragma unroll
      for (int n = 0; n < 4; ++n) {
        int c = bcol + wn * 64 + n * 16 + (l & 15);
        f32x4 v = aa[n] + acc[f][n];
#pragma unroll
        for (int j = 0; j < 4; ++j)
          out[(size_t)(rbase + j) * NDIM + c] = v[j];
      }
    }
  }
}

// ---------------------------------------------------------------------------
extern "C" void kernel_launch(void* const* d_in, const int* in_sizes, int n_in,
                              void* d_out, int out_size, void* d_ws, size_t ws_size,
                              hipStream_t stream)
{
  const int SD[9] = {33554432,16777216,262144,524288,262144,262144,16777216,4096,4096};
  const int SA[9] = {4096,16777216,262144,262144,262144,524288,4096,16777216,33554432};
  bool dict = (n_in == 9), alph = (n_in == 9);
  if (n_in == 9) {
    for (int i = 0; i < 9; ++i) {
      if (in_sizes[i] != SD[i]) dict = false;
      if (in_sizes[i] != SA[i]) alph = false;
    }
  }
  if (!dict && !alph) {
    int ix = 0;
    for (int i = 0; i < n_in; ++i)
      if (in_sizes[i] == 33554432 || in_sizes[i] == 134217728) { ix = i; break; }
    dict = (ix == 0);
  }
  const float* x     = (const float*)d_in[dict ? 0 : 8];
  const void*  fr    =               d_in[1];
  const float* L1    = (const float*)d_in[dict ? 2 : 4];
  const float* L2    = (const float*)d_in[dict ? 3 : 5];
  const float* gs    = (const float*)d_in[dict ? 4 : 3];
  const float* gb    = (const float*)d_in[dict ? 5 : 2];
  const float* sa    = (const float*)d_in[dict ? 6 : 7];
  const float* scale = (const float*)d_in[dict ? 7 : 6];
  const float* bias  = (const float*)d_in[dict ? 8 : 0];
  float* out = (float*)d_out;

  const size_t MW_B = (size_t)NDIM * KDIM * 2;    // 33,554,432
  const size_t XH_B = (size_t)8192 * KDIM * 2;    // 67,108,864

  char* ws = (char*)d_ws;
  // ws_size proven >= this layout by rounds 9-21 (T2 path executed).
  f16* mW  = (f16*)ws;
  f16* xh  = (f16*)(ws + MW_B);
  f16* hid = (f16*)(ws + MW_B + XH_B);

  k_prep2<<<dim3(24640), dim3(256), 0, stream>>>(
      x, fr, gs, gb, sa, L1, xh, mW, hid);
  k20_main<<<dim3(1024), dim3(512), 0, stream>>>(
      xh, mW, hid, L2, scale, bias, out);
}

// Round 23
// 435.183 us; speedup vs baseline: 1.2248x; 1.2248x over previous
//
#include <hip/hip_runtime.h>
#include <stdint.h>

typedef _Float16 f16;
typedef unsigned short u16;
typedef __attribute__((ext_vector_type(8))) _Float16 h16x8;
typedef __attribute__((ext_vector_type(8))) unsigned short u16x8;
typedef __attribute__((ext_vector_type(4))) float f32x4;

#define NDIM  4096
#define KDIM  4096
#define LRDIM 64
#define NTK   128        // KDIM / 32

#define MFMA16(a, b, c) __builtin_amdgcn_mfma_f32_16x16x32_f16((a), (b), (c), 0, 0, 0)

__device__ __forceinline__ float bf2f(u16 b) {
  union { unsigned u; float f; } c; c.u = ((unsigned)b) << 16; return c.f;
}
__device__ __forceinline__ float h2f(u16 b) {
  union { u16 u; f16 h; } c; c.u = b; return (float)c.h;
}
__device__ __forceinline__ h16x8 pack8(float4 a, float4 b) {
  h16x8 w = { (f16)a.x, (f16)a.y, (f16)a.z, (f16)a.w,
              (f16)b.x, (f16)b.y, (f16)b.z, (f16)b.w };
  return w;
}

// async global->LDS, 16B/lane; true addrspacecast (proven green r10-r21).
__device__ __forceinline__ void gll16(const void* g, void* l) {
  __builtin_amdgcn_global_load_lds(
      (const __attribute__((address_space(1))) void*)g,
      (__attribute__((address_space(3))) void*)l,
      16, 0, 0);
}

// ---------------------------------------------------------------------------
// frozen encoding classifier (proven): 0=f16, 1=bf16, 2=f32 halfword layout.
// ---------------------------------------------------------------------------
__device__ int frozen_mode(const void* frozen, int t) {
  const u16* fr = (const u16*)frozen;
  __shared__ int sE[256], sO[256];
  int ce = 0, co = 0;
  for (int j = 0; j < 8; ++j) {
    float ve = fabsf(bf2f(fr[t * 16 + 2 * j]));
    float vo = fabsf(bf2f(fr[t * 16 + 2 * j + 1]));
    if (ve >= 0.05f && ve <= 10.0f) ++ce;
    if (vo >= 0.05f && vo <= 10.0f) ++co;
  }
  sE[t] = ce; sO[t] = co;
  __syncthreads();
  for (int s = 128; s > 0; s >>= 1) {
    if (t < s) { sE[t] += sE[t + s]; sO[t] += sO[t + s]; }
    __syncthreads();
  }
  int te = sE[0], to = sO[0];
  __syncthreads();
  if (to > 1024) return (te > 1024) ? 1 : 2;
  return 0;
}

__device__ __forceinline__ h16x8 build_m8(
    const void* __restrict__ frozen, const float* __restrict__ gs,
    const float* __restrict__ gb, const float* __restrict__ sa,
    int o, int i0, int mode)
{
  size_t fo = (size_t)o * KDIM + i0;
  int gidx = (o >> 3) * 512 + (i0 >> 3);
  float gsf = gs[gidx], gbf = gb[gidx];
  float4 s0 = ((const float4*)(sa + fo))[0];
  float4 s1 = ((const float4*)(sa + fo))[1];
  float sv[8] = { s0.x, s0.y, s0.z, s0.w, s1.x, s1.y, s1.z, s1.w };
  float fv[8];
  if (mode == 2) {
    float4 q0 = ((const float4*)((const float*)frozen + fo))[0];
    float4 q1 = ((const float4*)((const float*)frozen + fo))[1];
    fv[0]=q0.x; fv[1]=q0.y; fv[2]=q0.z; fv[3]=q0.w;
    fv[4]=q1.x; fv[5]=q1.y; fv[6]=q1.z; fv[7]=q1.w;
  } else {
    u16x8 fb = *(const u16x8*)((const u16*)frozen + fo);
#pragma unroll
    for (int j = 0; j < 8; ++j) fv[j] = (mode == 1) ? bf2f(fb[j]) : h2f(fb[j]);
  }
  h16x8 w;
#pragma unroll
  for (int j = 0; j < 8; ++j) w[j] = (f16)(gbf + fv[j] * gsf + sv[j]);
  return w;
}

// ---------------------------------------------------------------------------
// k_prep: fused cast_x (blocks 0..16383) + build_m (16384..24575). (proven)
// ---------------------------------------------------------------------------
__global__ __launch_bounds__(256) void k_prep(
    const float* __restrict__ x, const void* __restrict__ frozen,
    const float* __restrict__ gs, const float* __restrict__ gb,
    const float* __restrict__ sa, f16* __restrict__ xh,
    f16* __restrict__ mW)
{
  int b = blockIdx.x;
  if (b < 16384) {
    size_t idx = (size_t)b * 256 + threadIdx.x;
    const float4* xp = (const float4*)x + idx * 2;
    *(h16x8*)(xh + idx * 8) = pack8(xp[0], xp[1]);
  } else {
    int mode = frozen_mode(frozen, threadIdx.x);
    int idx = (b - 16384) * 256 + threadIdx.x;
    int o  = idx >> 9;
    int ig = idx & 511;
    h16x8 w = build_m8(frozen, gs, gb, sa, o, ig * 8, mode);
    *(h16x8*)(mW + (size_t)o * KDIM + ig * 8) = w;
  }
}

// ---------------------------------------------------------------------------
// k14_hid (proven): hid = xh @ L1^T via MFMA, 256 blocks, BM=32.
// ---------------------------------------------------------------------------
__global__ __launch_bounds__(256) void k14_hid(const f16* __restrict__ xh,
                                               const float* __restrict__ L1,
                                               f16* __restrict__ hid)
{
  __shared__ f16 sA[2][32 * 32];
  __shared__ f16 sB[2][64 * 32];
  int t = threadIdx.x;
  int l = t & 63, wid = t >> 6;
  int wr = wid >> 1, wc = wid & 1;
  int brow = blockIdx.x * 32;
  int ar = t >> 2, ac8 = (t & 3) * 8;
  int brw = t >> 2, bc8 = (t & 3) * 8;

  f32x4 acc[2] = {};

  {
    if (t < 128)
      gll16(xh + (size_t)(brow + ar) * KDIM + ac8, &sA[0][ar * 32 + ac8]);
    const float* lp = L1 + (size_t)brw * KDIM + bc8;
    *(h16x8*)&sB[0][brw * 32 + bc8] = pack8(((const float4*)lp)[0], ((const float4*)lp)[1]);
  }

  int cur = 0;
  const int NT = KDIM / 32;
  for (int kt = 0; kt < NT; ++kt) {
    __syncthreads();
    bool pf = (kt + 1 < NT);
    h16x8 wb;
    if (pf) {
      int k0 = (kt + 1) * 32;
      if (t < 128)
        gll16(xh + (size_t)(brow + ar) * KDIM + k0 + ac8, &sA[cur ^ 1][ar * 32 + ac8]);
      const float* lp = L1 + (size_t)brw * KDIM + k0 + bc8;
      wb = pack8(((const float4*)lp)[0], ((const float4*)lp)[1]);
    }
    h16x8 aF, bF[2];
    aF = *(const h16x8*)&sA[cur][(wr * 16 + (l & 15)) * 32 + (l >> 4) * 8];
#pragma unroll
    for (int n = 0; n < 2; ++n)
      bF[n] = *(const h16x8*)&sB[cur][(wc * 32 + n * 16 + (l & 15)) * 32 + (l >> 4) * 8];
#pragma unroll
    for (int n = 0; n < 2; ++n)
      acc[n] = MFMA16(aF, bF[n], acc[n]);
    if (pf)
      *(h16x8*)&sB[cur ^ 1][brw * 32 + bc8] = wb;
    cur ^= 1;
  }

#pragma unroll
  for (int n = 0; n < 2; ++n)
#pragma unroll
    for (int j = 0; j < 4; ++j) {
      int r = wr * 16 + ((l >> 4) << 2) + j;
      int c = wc * 32 + n * 16 + (l & 15);
      hid[(size_t)(brow + r) * LRDIM + c] = (f16)acc[n][j];
    }
}

// ---------------------------------------------------------------------------
// k19b_main (proven r21, 298.6us): 256x128 tile, BK=32, 8 waves 2M x 4N
// (wave tile 128x32), 3 K-tile buffers (73.7KB -> 2 blocks/CU), 2-barrier +
// counted-gate schedule (vmcnt 6/3/0), src+read swizzle, XCD chunked map.
// ---------------------------------------------------------------------------
__global__ __launch_bounds__(512) void k19b_main(
    const f16* __restrict__ xh, const f16* __restrict__ mW,
    const f16* __restrict__ hid, const float* __restrict__ L2,
    const float* __restrict__ scale, const float* __restrict__ bias,
    float* __restrict__ out)
{
  __shared__ f16 lds[3 * 12288];    // 3 x (A[256][32] + B[128][32]) = 73,728 B

  int t = threadIdx.x;              // 0..511
  int l = t & 63, wid = t >> 6;     // 8 waves
  int wm = wid >> 2, wn = wid & 3;  // wave tile: rows wm*128..+128, cols wn*32..+32

  // XCD 2-D chunked mapping: 1024 blocks = 8 XCDs x 128
  int wg = blockIdx.x;
  int xcd = wg & 7, w = wg >> 3;    // w: 0..127
  int bm = xcd * 4 + (w & 3);       // 0..31
  int bn = w >> 2;                  // 0..31
  int brow = bm * 256, bcol = bn * 128;

  // stage one K-tile third (source-side swizzle: s_g = s_lds ^ ((r>>1)&3)).
  auto stage = [&](int q, int kt2, int buf) {
    int u = q * 512 + t;            // 0..1535
    if (u < 1024) {
      int sg = (u & 3) ^ ((u >> 3) & 3);
      gll16(xh + (size_t)(brow + (u >> 2)) * KDIM + kt2 * 32 + sg * 8,
            &lds[buf * 12288 + u * 8]);
    } else {
      int v = u - 1024;
      int sg = (v & 3) ^ ((v >> 3) & 3);
      gll16(mW + (size_t)(bcol + (v >> 2)) * KDIM + kt2 * 32 + sg * 8,
            &lds[buf * 12288 + 8192 + v * 8]);
    }
  };

  // ---- prologue: stage K-tiles 0 (buf0) and 1 (buf1) ----
#pragma unroll
  for (int q = 0; q < 3; ++q) stage(q, 0, 0);
#pragma unroll
  for (int q = 0; q < 3; ++q) stage(q, 1, 1);

  f32x4 acc[8][2] = {};

  // read-side swizzle (lane-constant)
  int X = ((l >> 4) ^ ((l >> 1) & 3)) * 8;

  for (int kt = 0; kt < NTK; ++kt) {
    const f16* A = &lds[(kt % 3) * 12288];
    const f16* B = &lds[(kt % 3) * 12288 + 8192];
    int sb = (kt + 2) % 3;

    if (kt + 2 < NTK) {
#pragma unroll
      for (int q = 0; q < 3; ++q) stage(q, kt + 2, sb);
    }

    // residency gate for tile kt (3 loads/thread/tile)
    if (kt < NTK - 2) {
      asm volatile("s_waitcnt vmcnt(6)" ::: "memory");
    } else if (kt == NTK - 2) {
      asm volatile("s_waitcnt vmcnt(3)" ::: "memory");
    } else {
      asm volatile("s_waitcnt vmcnt(0)" ::: "memory");
    }
    __builtin_amdgcn_sched_barrier(0);
    __builtin_amdgcn_s_barrier();   // G: tile kt resident for all waves

    int ar0 = (wm * 128 + (l & 15)) * 32 + X;
    int br0 = (wn * 32  + (l & 15)) * 32 + X;

    h16x8 aF[8], bF[2];
#pragma unroll
    for (int f = 0; f < 8; ++f) aF[f] = *(const h16x8*)&A[ar0 + f * 512];
#pragma unroll
    for (int n = 0; n < 2; ++n) bF[n] = *(const h16x8*)&B[br0 + n * 512];

    __builtin_amdgcn_s_setprio(1);
#pragma unroll
    for (int f = 0; f < 8; ++f)
#pragma unroll
      for (int n = 0; n < 2; ++n)
        acc[f][n] = MFMA16(aF[f], bF[n], acc[f][n]);
    __builtin_amdgcn_s_setprio(0);

    __builtin_amdgcn_s_barrier();   // E: all reads of buf[kt%3] done
  }

  // ---- fused epilogue: sH[256][64] + sLm[128][64] + sLa[128][64] ----
  f16* sH  = &lds[0];               // 16384 f16 (32 KB)
  f16* sLm = &lds[16384];           //  8192 f16
  f16* sLa = &lds[24576];           //  8192 f16

#pragma unroll
  for (int q = 0; q < 4; ++q) {     // sH: 2048 16B-units
    int u = q * 512 + t;
    gll16(hid + (size_t)(brow + (u >> 3)) * LRDIM + (u & 7) * 8, &sH[u * 8]);
  }
#pragma unroll
  for (int q = 0; q < 2; ++q) {     // sLm: 1024 units
    int u = q * 512 + t;
    const float* lp = L2 + (size_t)(bcol + (u >> 3)) * LRDIM + (u & 7) * 8;
    *(h16x8*)&sLm[u * 8] = pack8(((const float4*)lp)[0], ((const float4*)lp)[1]);
  }
#pragma unroll
  for (int q = 0; q < 2; ++q) {     // sLa: 1024 units
    int u = q * 512 + t;
    const float* lq = L2 + (size_t)(NDIM + bcol + (u >> 3)) * LRDIM + (u & 7) * 8;
    *(h16x8*)&sLa[u * 8] = pack8(((const float4*)lq)[0], ((const float4*)lq)[1]);
  }
  __syncthreads();                  // full drain before reads

  float sc[2], bi[2];
#pragma unroll
  for (int n = 0; n < 2; ++n) {
    int o = bcol + wn * 32 + n * 16 + (l & 15);
    sc[n] = scale[o];
    bi[n] = bias[o];
  }

  // pass 1: mul = hid @ L2[0:4096]^T + scale ; acc <- mul * acc
  {
    h16x8 lB[2][2];
#pragma unroll
    for (int n = 0; n < 2; ++n)
#pragma unroll
      for (int kk = 0; kk < 2; ++kk)
        lB[n][kk] = *(const h16x8*)&sLm[(wn * 32 + n * 16 + (l & 15)) * 64 + kk * 32 + (l >> 4) * 8];
#pragma unroll
    for (int f = 0; f < 8; ++f) {
      h16x8 h0 = *(const h16x8*)&sH[(wm * 128 + f * 16 + (l & 15)) * 64 + (l >> 4) * 8];
      h16x8 h1 = *(const h16x8*)&sH[(wm * 128 + f * 16 + (l & 15)) * 64 + 32 + (l >> 4) * 8];
      f32x4 mm[2];
#pragma unroll
      for (int n = 0; n < 2; ++n) {
        f32x4 mi = { sc[n], sc[n], sc[n], sc[n] };
        mm[n] = mi;
      }
#pragma unroll
      for (int n = 0; n < 2; ++n) {
        mm[n] = MFMA16(h0, lB[n][0], mm[n]);
        mm[n] = MFMA16(h1, lB[n][1], mm[n]);
      }
#pragma unroll
      for (int n = 0; n < 2; ++n)
        acc[f][n] *= mm[n];
    }
  }

  // pass 2: add = hid @ L2[4096:8192]^T + bias ; out = add + acc
  {
    h16x8 lB[2][2];
#pragma unroll
    for (int n = 0; n < 2; ++n)
#pragma unroll
      for (int kk = 0; kk < 2; ++kk)
        lB[n][kk] = *(const h16x8*)&sLa[(wn * 32 + n * 16 + (l & 15)) * 64 + kk * 32 + (l >> 4) * 8];
#pragma unroll
    for (int f = 0; f < 8; ++f) {
      h16x8 h0 = *(const h16x8*)&sH[(wm * 128 + f * 16 + (l & 15)) * 64 + (l >> 4) * 8];
      h16x8 h1 = *(const h16x8*)&sH[(wm * 128 + f * 16 + (l & 15)) * 64 + 32 + (l >> 4) * 8];
      f32x4 aa[2];
#pragma unroll
      for (int n = 0; n < 2; ++n) {
        f32x4 mi = { bi[n], bi[n], bi[n], bi[n] };
        aa[n] = mi;
      }
#pragma unroll
      for (int n = 0; n < 2; ++n) {
        aa[n] = MFMA16(h0, lB[n][0], aa[n]);
        aa[n] = MFMA16(h1, lB[n][1], aa[n]);
      }
      int rbase = brow + wm * 128 + f * 16 + ((l >> 4) << 2);
#pragma unroll
      for (int n = 0; n < 2; ++n) {
        int c = bcol + wn * 32 + n * 16 + (l & 15);
        f32x4 v = aa[n] + acc[f][n];
#pragma unroll
        for (int j = 0; j < 4; ++j)
          out[(size_t)(rbase + j) * NDIM + c] = v[j];
      }
    }
  }
}

// ---------------------------------------------------------------------------
extern "C" void kernel_launch(void* const* d_in, const int* in_sizes, int n_in,
                              void* d_out, int out_size, void* d_ws, size_t ws_size,
                              hipStream_t stream)
{
  const int SD[9] = {33554432,16777216,262144,524288,262144,262144,16777216,4096,4096};
  const int SA[9] = {4096,16777216,262144,262144,262144,524288,4096,16777216,33554432};
  bool dict = (n_in == 9), alph = (n_in == 9);
  if (n_in == 9) {
    for (int i = 0; i < 9; ++i) {
      if (in_sizes[i] != SD[i]) dict = false;
      if (in_sizes[i] != SA[i]) alph = false;
    }
  }
  if (!dict && !alph) {
    int ix = 0;
    for (int i = 0; i < n_in; ++i)
      if (in_sizes[i] == 33554432 || in_sizes[i] == 134217728) { ix = i; break; }
    dict = (ix == 0);
  }
  const float* x     = (const float*)d_in[dict ? 0 : 8];
  const void*  fr    =               d_in[1];
  const float* L1    = (const float*)d_in[dict ? 2 : 4];
  const float* L2    = (const float*)d_in[dict ? 3 : 5];
  const float* gs    = (const float*)d_in[dict ? 4 : 3];
  const float* gb    = (const float*)d_in[dict ? 5 : 2];
  const float* sa    = (const float*)d_in[dict ? 6 : 7];
  const float* scale = (const float*)d_in[dict ? 7 : 6];
  const float* bias  = (const float*)d_in[dict ? 8 : 0];
  float* out = (float*)d_out;

  const size_t MW_B = (size_t)NDIM * KDIM * 2;    // 33,554,432
  const size_t XH_B = (size_t)8192 * KDIM * 2;    // 67,108,864

  char* ws = (char*)d_ws;
  // ws_size proven >= this layout by rounds 9-22 (T2 path executed).
  f16* mW  = (f16*)ws;
  f16* xh  = (f16*)(ws + MW_B);
  f16* hid = (f16*)(ws + MW_B + XH_B);

  k_prep<<<dim3(24576), dim3(256), 0, stream>>>(x, fr, gs, gb, sa, xh, mW);
  k14_hid<<<dim3(256), dim3(256), 0, stream>>>(xh, L1, hid);
  k19b_main<<<dim3(1024), dim3(512), 0, stream>>>(
      xh, mW, hid, L2, scale, bias, out);
}